// Round 15
// baseline (2016.362 us; speedup 1.0000x reference)
//
#include <hip/hip_runtime.h>
#include <hip/hip_fp16.h>

typedef __attribute__((ext_vector_type(8))) short short8;
typedef __attribute__((ext_vector_type(8))) unsigned short ushort8;
typedef __attribute__((ext_vector_type(4))) float f32x4;
typedef unsigned long long ull;

__device__ __forceinline__ unsigned short f2bf(float f){
  unsigned u = __float_as_uint(f);
  u += 0x7FFFu + ((u >> 16) & 1u);
  return (unsigned short)(u >> 16);
}
__device__ __forceinline__ float sigm(float x){ return 1.f / (1.f + expf(-x)); }
__device__ __forceinline__ int aldr(const int* p){
  return __hip_atomic_load(p, __ATOMIC_RELAXED, __HIP_MEMORY_SCOPE_AGENT);
}
__device__ __forceinline__ ull ald8(const ull* p){
  return __hip_atomic_load(p, __ATOMIC_RELAXED, __HIP_MEMORY_SCOPE_AGENT);
}
__device__ __forceinline__ void ast8(ull* p, ull v){
  __hip_atomic_store(p, v, __ATOMIC_RELAXED, __HIP_MEMORY_SCOPE_AGENT);
}
__device__ __forceinline__ void asti(int* p, int v){
  __hip_atomic_store(p, v, __ATOMIC_RELAXED, __HIP_MEMORY_SCOPE_AGENT);
}
__device__ __forceinline__ ull pack2(float he, float ho, unsigned tag){
  unsigned lo = (unsigned)__half_as_ushort(__float2half(he))
              | ((unsigned)__half_as_ushort(__float2half(ho)) << 16);
  return ((ull)tag << 32) | (ull)lo;
}
__device__ __forceinline__ void up2(unsigned w, float& a, float& b){
  a = __half2float(__ushort_as_half((unsigned short)w));
  b = __half2float(__ushort_as_half((unsigned short)(w >> 16)));
}

// ---------- prep kernels ----------

__global__ void k_embed_cvt(const float* __restrict__ e, unsigned short* __restrict__ ebf){
  long i = ((long)blockIdx.x * 256 + threadIdx.x) * 4;
  float4 v = *(const float4*)(e + i);
  ushort4 o;
  o.x = f2bf(v.x); o.y = f2bf(v.y); o.z = f2bf(v.z); o.w = f2bf(v.w);
  *(ushort4*)(ebf + i) = o;
}

__global__ void k_prep_misc(const float* __restrict__ b_ih2, const float* __restrict__ b_hh2,
                            float* __restrict__ b2c, ull* __restrict__ h1tag0,
                            ull* __restrict__ h2tag0, unsigned short* __restrict__ h2bf0,
                            int* __restrict__ done){
  int i = blockIdx.x * 256 + threadIdx.x;   // 8192 threads
  if(i < 4096){ h1tag0[i] = 0ull; h2tag0[i] = 0ull; }
  h2bf0[i] = 0;
  if(i < 2048){ b2c[i] = b_ih2[i] + b_hh2[i]; }
  if(i < 4096){ done[i] = 0; }
}

__global__ void k_a1const(const int* __restrict__ words, const float* __restrict__ embed,
                          const float* __restrict__ w_ih1, const float* __restrict__ b_ih1,
                          const float* __restrict__ b_hh1, float* __restrict__ a1c){
  int bb = threadIdx.x & 15, jj = threadIdx.x >> 4;
  int j = blockIdx.x * 16 + jj;
  const float* x0 = embed + (long)words[bb * 256] * 512;
  const float* wr = w_ih1 + (long)j * 1024;
  float acc = 0.f;
  for(int k = 0; k < 512; k += 4){
    float4 a = *(const float4*)(x0 + k);
    float4 b = *(const float4*)(wr + k);
    acc += a.x*b.x + a.y*b.y + a.z*b.z + a.w*b.w;
  }
  a1c[bb * 2048 + j] = acc + b_ih1[j] + b_hh1[j];
}

// ---------- recurrent kernel: fp16 wire, raw-u32 LDS stage, slim 4-barrier L2 ----------
// 256 blocks. bl<128: layer-1 (fp16 W1 16KB + u32 stage 16KB + 2KB prt, 2 barriers).
// bl>=128: layer-2 (fp16 W2 32KB + stgA/stgB 16KB each, prt overlays dead stgA, 4 barriers).
// Exchange: {tag, 2xfp16} 8B relaxed agent atomics, ring depth 64. Coop launch + fallback.
__global__ void __launch_bounds__(256) k_recur(
    const float* __restrict__ w_hh1, const float* __restrict__ w_ih2, const float* __restrict__ w_hh2,
    const float* __restrict__ a1c, const float* __restrict__ b2c,
    ull* __restrict__ h1tag, ull* __restrict__ h2tag, unsigned short* __restrict__ h2bf,
    int* done){
  __shared__ unsigned smem32[16384];      // 64KB
  int* prog2 = done + 2048;               // L2 progress watermark, flag i at [i*16]
  const int bl = blockIdx.x, tid = threadIdx.x;
  const int cg = tid & 3, kg = (tid >> 2) & 31, bh = tid >> 7;
  const bool isL1 = (bl < 128);
  const int ubase = (isL1 ? bl : bl - 128) * 4;
  const int gb = tid >> 4, gu = tid & 3;
  const bool gate = ((tid & 12) == 0);
  const int swp_tid = tid ^ (((tid >> 5) & 3) << 2);   // stage-write swizzled pair slot

  // ---- stage weights into LDS (once; R14-proven) ----
  if(isL1){
    unsigned short* W1h = (unsigned short*)smem32;      // 16 cols x 512 fp16 = 16KB
    #pragma unroll
    for(int q = 0; q < 4; ++q){
      int f = q * 256 + tid;
      int col = f >> 6, sk = f & 63;
      int row = (col >> 2) * 512 + ubase + (col & 3);
      const float* srcw = w_hh1 + (long)row * 512 + sk * 8;
      float4 va = *(const float4*)(srcw);
      float4 vb = *(const float4*)(srcw + 4);
      ushort8 o;
      o[0] = __half_as_ushort(__float2half(va.x)); o[1] = __half_as_ushort(__float2half(va.y));
      o[2] = __half_as_ushort(__float2half(va.z)); o[3] = __half_as_ushort(__float2half(va.w));
      o[4] = __half_as_ushort(__float2half(vb.x)); o[5] = __half_as_ushort(__float2half(vb.y));
      o[6] = __half_as_ushort(__float2half(vb.z)); o[7] = __half_as_ushort(__float2half(vb.w));
      int key = (col + (col >> 2)) & 7;
      *(ushort8*)(W1h + col * 512 + (sk ^ key) * 8) = o;
    }
  } else {
    unsigned short* W2 = (unsigned short*)smem32;       // 16 cols x 1024 fp16 = 32KB
    #pragma unroll
    for(int q = 0; q < 8; ++q){
      int f = q * 256 + tid;
      int col = f >> 7, sk = f & 127;
      int row = (col >> 2) * 512 + ubase + (col & 3);
      int k = sk * 8;
      const float* srcw = (k < 512) ? (w_ih2 + (long)row * 512 + k)
                                    : (w_hh2 + (long)row * 512 + (k - 512));
      float4 va = *(const float4*)(srcw);
      float4 vb = *(const float4*)(srcw + 4);
      ushort8 o;
      o[0] = __half_as_ushort(__float2half(va.x)); o[1] = __half_as_ushort(__float2half(va.y));
      o[2] = __half_as_ushort(__float2half(va.z)); o[3] = __half_as_ushort(__float2half(va.w));
      o[4] = __half_as_ushort(__float2half(vb.x)); o[5] = __half_as_ushort(__float2half(vb.y));
      o[6] = __half_as_ushort(__float2half(vb.z)); o[7] = __half_as_ushort(__float2half(vb.w));
      int key = (col + (col >> 2)) & 7;
      *(ushort8*)(W2 + col * 1024 + (sk ^ key) * 8) = o;
    }
  }
  float ag[4] = {0.f, 0.f, 0.f, 0.f};
  float cst = 0.f;
  if(gate){
    #pragma unroll
    for(int g = 0; g < 4; ++g)
      ag[g] = isL1 ? a1c[gb * 2048 + g * 512 + ubase + gu] : b2c[g * 512 + ubase + gu];
  }
  __syncthreads();

  if(isL1){
    // ================= layer 1: 2-barrier step =================
    unsigned* stg = smem32 + 4096;        // u32 pairs, 16KB
    float* prt = (float*)(smem32 + 8192); // 2KB partials
    const unsigned short* W1h = (const unsigned short*)smem32;
    for(int s = 1; s <= 255; ++s){
      if(((s & 15) == 1) && s > 48 && tid < 64){
        for(;;){
          int ok = (aldr(prog2 + tid * 16) >= s - 40) & (aldr(prog2 + (64 + tid) * 16) >= s - 40);
          if(__all(ok)) break;
          __builtin_amdgcn_s_sleep(1);
        }
      }
      // ---- spin-stage h1(s-1) ----
      {
        const ull* src = h1tag + ((s - 1) & 63) * 4096;
        const unsigned want = (unsigned)(s - 1);
        ull v[16];
        #pragma unroll
        for(int j = 0; j < 16; ++j) v[j] = ald8(src + tid + 256 * j);
        for(;;){
          bool bad = false;
          #pragma unroll
          for(int j = 0; j < 16; ++j)
            if((unsigned)(v[j] >> 32) != want){ v[j] = ald8(src + tid + 256 * j); bad = true; }
          if(!bad) break;
        }
        #pragma unroll
        for(int j = 0; j < 16; ++j) stg[j * 256 + swp_tid] = (unsigned)v[j];
      }
      __syncthreads();                    // B1: stage -> dot
      float acc[8][4] = {};
      #pragma unroll
      for(int jbp = 0; jbp < 2; ++jbp){
        float wf[4][8];
        #pragma unroll
        for(int cc = 0; cc < 4; ++cc){
          int col = cg * 4 + cc;
          int sk = kg * 2 + jbp;
          ushort8 wv = *(const ushort8*)(W1h + col * 512 + ((sk ^ ((col + (col >> 2)) & 7)) * 8));
          #pragma unroll
          for(int e = 0; e < 8; ++e) wf[cc][e] = __half2float(__ushort_as_half(wv[e]));
        }
        int base = 8 * kg + 4 * jbp;
        int idx = base ^ (((base >> 5) & 3) << 2);
        #pragma unroll
        for(int b8 = 0; b8 < 8; ++b8){
          uint4 hp = *(const uint4*)(stg + (bh * 8 + b8) * 256 + idx);
          float h0,h1,h2,h3,h4,h5,h6,h7;
          up2(hp.x, h0, h1); up2(hp.y, h2, h3); up2(hp.z, h4, h5); up2(hp.w, h6, h7);
          #pragma unroll
          for(int cc = 0; cc < 4; ++cc)
            acc[b8][cc] += h0*wf[cc][0] + h1*wf[cc][1] + h2*wf[cc][2] + h3*wf[cc][3]
                         + h4*wf[cc][4] + h5*wf[cc][5] + h6*wf[cc][6] + h7*wf[cc][7];
        }
      }
      #pragma unroll
      for(int m = 4; m <= 32; m <<= 1){
        #pragma unroll
        for(int b8 = 0; b8 < 8; ++b8)
          #pragma unroll
          for(int cc = 0; cc < 4; ++cc)
            acc[b8][cc] += __shfl_xor(acc[b8][cc], m);
      }
      if((tid & 60) == 0){
        int w = tid >> 6;
        #pragma unroll
        for(int cc = 0; cc < 4; ++cc)
          #pragma unroll
          for(int b8 = 0; b8 < 8; ++b8)
            prt[w * 128 + cg * 32 + cc * 8 + b8] = acc[b8][cc];
      }
      __syncthreads();                    // B2: partials -> gates
      {
        int bhh = gb >> 3, b8g = gb & 7;
        float g0 = prt[(bhh*2)*128 + 0*32 + gu*8 + b8g] + prt[(bhh*2+1)*128 + 0*32 + gu*8 + b8g] + ag[0];
        float g1 = prt[(bhh*2)*128 + 1*32 + gu*8 + b8g] + prt[(bhh*2+1)*128 + 1*32 + gu*8 + b8g] + ag[1];
        float g2 = prt[(bhh*2)*128 + 2*32 + gu*8 + b8g] + prt[(bhh*2+1)*128 + 2*32 + gu*8 + b8g] + ag[2];
        float g3 = prt[(bhh*2)*128 + 3*32 + gu*8 + b8g] + prt[(bhh*2+1)*128 + 3*32 + gu*8 + b8g] + ag[3];
        cst = sigm(g1) * cst + sigm(g0) * tanhf(g2);
        float h = sigm(g3) * tanhf(cst);
        float hn = __shfl(h, ((tid & 63) + 1) & 63);
        if(gate && (gu & 1) == 0)
          ast8(h1tag + (s & 63) * 4096 + gb * 256 + bl * 2 + (gu >> 1), pack2(h, hn, (unsigned)s));
      }
      // no end barrier: stg/prt WAR protected by B1/B2 of the next iteration
    }
  } else {
    // ================= layer 2: 4-barrier step =================
    unsigned* stgA = smem32 + 8192;       // h1(s) pairs, 16KB
    unsigned* stgB = smem32 + 12288;      // h2(s-1) pairs, 16KB
    float* prt = (float*)stgA;            // overlays stgA (dead after B2)
    const unsigned short* W2 = (const unsigned short*)smem32;
    for(int s = 1; s <= 255; ++s){
      float acc[8][4] = {};
      const ull* s1 = h1tag + (s & 63) * 4096;           // want tag s
      const ull* s2 = h2tag + ((s - 1) & 63) * 4096;     // want tag s-1
      const unsigned w1 = (unsigned)s, w2 = (unsigned)(s - 1);
      ull v1[16], v2[16];
      #pragma unroll
      for(int j = 0; j < 16; ++j) v1[j] = ald8(s1 + tid + 256 * j);
      #pragma unroll
      for(int j = 0; j < 16; ++j) v2[j] = ald8(s2 + tid + 256 * j);
      for(;;){
        bool bad = false;
        #pragma unroll
        for(int j = 0; j < 16; ++j)
          if((unsigned)(v1[j] >> 32) != w1){ v1[j] = ald8(s1 + tid + 256 * j); bad = true; }
        if(!bad) break;
      }
      #pragma unroll
      for(int j = 0; j < 16; ++j) stgA[j * 256 + swp_tid] = (unsigned)v1[j];
      __syncthreads();                    // B1: stageA -> dot0
      // dot0 (K = h1(s))
      #pragma unroll
      for(int jbp = 0; jbp < 2; ++jbp){
        float wf[4][8];
        #pragma unroll
        for(int cc = 0; cc < 4; ++cc){
          int col = cg * 4 + cc;
          int sk = kg * 2 + jbp;
          ushort8 wv = *(const ushort8*)(W2 + col * 1024 + ((sk ^ ((col + (col >> 2)) & 7)) * 8));
          #pragma unroll
          for(int e = 0; e < 8; ++e) wf[cc][e] = __half2float(__ushort_as_half(wv[e]));
        }
        int base = 8 * kg + 4 * jbp;
        int idx = base ^ (((base >> 5) & 3) << 2);
        #pragma unroll
        for(int b8 = 0; b8 < 8; ++b8){
          uint4 hp = *(const uint4*)(stgA + (bh * 8 + b8) * 256 + idx);
          float h0,h1,h2,h3,h4,h5,h6,h7;
          up2(hp.x, h0, h1); up2(hp.y, h2, h3); up2(hp.z, h4, h5); up2(hp.w, h6, h7);
          #pragma unroll
          for(int cc = 0; cc < 4; ++cc)
            acc[b8][cc] += h0*wf[cc][0] + h1*wf[cc][1] + h2*wf[cc][2] + h3*wf[cc][3]
                         + h4*wf[cc][4] + h5*wf[cc][5] + h6*wf[cc][6] + h7*wf[cc][7];
        }
      }
      // spin-fix h2 chunk (loads long in flight) and stage into stgB (disjoint region, no barrier)
      for(;;){
        bool bad = false;
        #pragma unroll
        for(int j = 0; j < 16; ++j)
          if((unsigned)(v2[j] >> 32) != w2){ v2[j] = ald8(s2 + tid + 256 * j); bad = true; }
        if(!bad) break;
      }
      #pragma unroll
      for(int j = 0; j < 16; ++j) stgB[j * 256 + swp_tid] = (unsigned)v2[j];
      __syncthreads();                    // B2: stageB complete + dot0's stgA reads done
      // dot1 (K = h2(s-1))
      #pragma unroll
      for(int jbp = 0; jbp < 2; ++jbp){
        float wf[4][8];
        #pragma unroll
        for(int cc = 0; cc < 4; ++cc){
          int col = cg * 4 + cc;
          int sk = 64 + kg * 2 + jbp;
          ushort8 wv = *(const ushort8*)(W2 + col * 1024 + ((sk ^ ((col + (col >> 2)) & 7)) * 8));
          #pragma unroll
          for(int e = 0; e < 8; ++e) wf[cc][e] = __half2float(__ushort_as_half(wv[e]));
        }
        int base = 8 * kg + 4 * jbp;
        int idx = base ^ (((base >> 5) & 3) << 2);
        #pragma unroll
        for(int b8 = 0; b8 < 8; ++b8){
          uint4 hp = *(const uint4*)(stgB + (bh * 8 + b8) * 256 + idx);
          float h0,h1,h2,h3,h4,h5,h6,h7;
          up2(hp.x, h0, h1); up2(hp.y, h2, h3); up2(hp.z, h4, h5); up2(hp.w, h6, h7);
          #pragma unroll
          for(int cc = 0; cc < 4; ++cc)
            acc[b8][cc] += h0*wf[cc][0] + h1*wf[cc][1] + h2*wf[cc][2] + h3*wf[cc][3]
                         + h4*wf[cc][4] + h5*wf[cc][5] + h6*wf[cc][6] + h7*wf[cc][7];
        }
      }
      #pragma unroll
      for(int m = 4; m <= 32; m <<= 1){
        #pragma unroll
        for(int b8 = 0; b8 < 8; ++b8)
          #pragma unroll
          for(int cc = 0; cc < 4; ++cc)
            acc[b8][cc] += __shfl_xor(acc[b8][cc], m);
      }
      if((tid & 60) == 0){
        int w = tid >> 6;
        #pragma unroll
        for(int cc = 0; cc < 4; ++cc)
          #pragma unroll
          for(int b8 = 0; b8 < 8; ++b8)
            prt[w * 128 + cg * 32 + cc * 8 + b8] = acc[b8][cc];   // stgA dead since B2
      }
      __syncthreads();                    // B3: partials -> gates
      {
        int bhh = gb >> 3, b8g = gb & 7;
        float g0 = prt[(bhh*2)*128 + 0*32 + gu*8 + b8g] + prt[(bhh*2+1)*128 + 0*32 + gu*8 + b8g] + ag[0];
        float g1 = prt[(bhh*2)*128 + 1*32 + gu*8 + b8g] + prt[(bhh*2+1)*128 + 1*32 + gu*8 + b8g] + ag[1];
        float g2 = prt[(bhh*2)*128 + 2*32 + gu*8 + b8g] + prt[(bhh*2+1)*128 + 2*32 + gu*8 + b8g] + ag[2];
        float g3 = prt[(bhh*2)*128 + 3*32 + gu*8 + b8g] + prt[(bhh*2+1)*128 + 3*32 + gu*8 + b8g] + ag[3];
        cst = sigm(g1) * cst + sigm(g0) * tanhf(g2);
        float h = sigm(g3) * tanhf(cst);
        float hn = __shfl(h, ((tid & 63) + 1) & 63);
        if(gate){
          if((gu & 1) == 0)
            ast8(h2tag + (s & 63) * 4096 + gb * 256 + (bl - 128) * 2 + (gu >> 1),
                 pack2(h, hn, (unsigned)s));
          h2bf[((long)s * 16 + gb) * 512 + ubase + gu] = f2bf(h);
        }
      }
      __syncthreads();                    // B4: prt reads done before next stageA overlay
      if(tid == 0) asti(prog2 + (bl - 128) * 16, s);
    }
  }
}

// ---------- projection GEMM (unchanged, passing) ----------
__global__ void __launch_bounds__(256, 2) k_proj(const unsigned short* __restrict__ A,
                                                 const unsigned short* __restrict__ Bm,
                                                 const float* __restrict__ fc_b,
                                                 float* __restrict__ out){
  __shared__ __align__(16) unsigned short As[4096];   // [128][32]
  __shared__ __align__(16) unsigned short Bs[4096];   // [128][32]
  const int tid = threadIdx.x;
  const int lane = tid & 63, w = tid >> 6;
  const int wr = w >> 1, wc = w & 1;
  const long mbase = (long)blockIdx.y * 128;
  const long nbase = (long)blockIdx.x * 128;
  f32x4 acc[4][4] = {};

  const int lrow = lane >> 2;
  const int lcol = (lane & 3) * 8;
  for(int kt = 0; kt < 16; ++kt){
    #pragma unroll
    for(int r = 0; r < 2; ++r){
      const unsigned short* ga = A  + (mbase + r*64 + w*16 + lrow) * 512 + kt*32 + lcol;
      __builtin_amdgcn_global_load_lds((const __attribute__((address_space(1))) void*)ga,
          (__attribute__((address_space(3))) void*)((char*)As + r*4096 + w*1024), 16, 0, 0);
      const unsigned short* gb = Bm + (nbase + r*64 + w*16 + lrow) * 512 + kt*32 + lcol;
      __builtin_amdgcn_global_load_lds((const __attribute__((address_space(1))) void*)gb,
          (__attribute__((address_space(3))) void*)((char*)Bs + r*4096 + w*1024), 16, 0, 0);
    }
    __syncthreads();
    short8 af[4], bf[4];
    const int kro = (lane >> 4) * 8;
    #pragma unroll
    for(int m = 0; m < 4; ++m){
      af[m] = *(const short8*)(As + (wr*64 + m*16 + (lane & 15)) * 32 + kro);
      bf[m] = *(const short8*)(Bs + (wc*64 + m*16 + (lane & 15)) * 32 + kro);
    }
    #pragma unroll
    for(int m = 0; m < 4; ++m){
      #pragma unroll
      for(int n = 0; n < 4; ++n){
        acc[m][n] = __builtin_amdgcn_mfma_f32_16x16x32_bf16(af[m], bf[n], acc[m][n], 0, 0, 0);
      }
    }
    __syncthreads();
  }
  const int crow0 = (lane >> 4) * 4;
  const int ccol = lane & 15;
  float fb[4];
  #pragma unroll
  for(int n = 0; n < 4; ++n) fb[n] = fc_b[nbase + wc*64 + n*16 + ccol];
  #pragma unroll
  for(int m = 0; m < 4; ++m){
    #pragma unroll
    for(int j = 0; j < 4; ++j){
      long rr = mbase + wr*64 + m*16 + crow0 + j;
      int t = (int)(rr >> 4), b = (int)(rr & 15);
      float* orow = out + ((long)b * 256 + t) * 32000;
      #pragma unroll
      for(int n = 0; n < 4; ++n){
        float v = (t == 0) ? 0.f : (acc[m][n][j] + fb[n]);
        orow[nbase + wc*64 + n*16 + ccol] = v;
      }
    }
  }
}

extern "C" void kernel_launch(void* const* d_in, const int* in_sizes, int n_in,
                              void* d_out, int out_size, void* d_ws, size_t ws_size,
                              hipStream_t stream){
  const int*   words = (const int*)  d_in[0];
  const float* embed = (const float*)d_in[1];
  const float* fc_b  = (const float*)d_in[2];
  const float* w_ih1 = (const float*)d_in[3];
  const float* w_hh1 = (const float*)d_in[4];
  const float* b_ih1 = (const float*)d_in[5];
  const float* b_hh1 = (const float*)d_in[6];
  const float* w_ih2 = (const float*)d_in[7];
  const float* w_hh2 = (const float*)d_in[8];
  const float* b_ih2 = (const float*)d_in[9];
  const float* b_hh2 = (const float*)d_in[10];
  float* out = (float*)d_out;
  char* ws = (char*)d_ws;

  unsigned short* embed_bf = (unsigned short*)(ws + 0);          // 32,768,000 B
  unsigned short* h2bf     = (unsigned short*)(ws + 32768000);   //  4,194,304 B (4096x512)
  ull* h1tag = (ull*)(ws + 36962304);                            //  2,097,152 B (64 x 4096 ull)
  ull* h2tag = (ull*)(ws + 39059456);                            //  2,097,152 B
  float* a1c = (float*)(ws + 41156608);                          //    131,072 B (16x2048)
  float* b2c = (float*)(ws + 41287680);                          //      8,192 B
  int*   done = (int*) (ws + 41295872);                          //     16,384 B (4096 ints)
  // total 41,312,256 B

  k_embed_cvt<<<16000, 256, 0, stream>>>(embed, embed_bf);
  k_prep_misc<<<32, 256, 0, stream>>>(b_ih2, b_hh2, b2c, h1tag, h2tag, h2bf, done);
  k_a1const<<<128, 256, 0, stream>>>(words, embed, w_ih1, b_ih1, b_hh1, a1c);

  // k_recur needs only de-facto co-residency (no grid.sync). Coop launch when the
  // runtime accepts it; otherwise plain launch (the R3..R9 silent-failure fix).
  void* args[9];
  args[0] = (void*)&w_hh1; args[1] = (void*)&w_ih2; args[2] = (void*)&w_hh2;
  args[3] = (void*)&a1c;   args[4] = (void*)&b2c;
  args[5] = (void*)&h1tag; args[6] = (void*)&h2tag; args[7] = (void*)&h2bf;
  args[8] = (void*)&done;
  hipError_t ce = hipLaunchCooperativeKernel((const void*)k_recur, dim3(256), dim3(256),
                                             args, 0, stream);
  if(ce != hipSuccess){
    k_recur<<<dim3(256), dim3(256), 0, stream>>>(w_hh1, w_ih2, w_hh2, a1c, b2c,
                                                 h1tag, h2tag, h2bf, done);
  }

  k_proj<<<dim3(250, 32), 256, 0, stream>>>(h2bf, embed_bf, fc_b, out);
}

// Round 16
// 1769.670 us; speedup vs baseline: 1.1394x; 1.1394x over previous
//
#include <hip/hip_runtime.h>

typedef __attribute__((ext_vector_type(8))) short short8;
typedef __attribute__((ext_vector_type(4))) float f32x4;
typedef unsigned long long ull;

__device__ __forceinline__ unsigned short f2bf(float f){
  unsigned u = __float_as_uint(f);
  u += 0x7FFFu + ((u >> 16) & 1u);
  return (unsigned short)(u >> 16);
}
__device__ __forceinline__ float sigm(float x){ return 1.f / (1.f + expf(-x)); }
__device__ __forceinline__ int aldr(const int* p){
  return __hip_atomic_load(p, __ATOMIC_RELAXED, __HIP_MEMORY_SCOPE_AGENT);
}
__device__ __forceinline__ ull ald8(const ull* p){
  return __hip_atomic_load(p, __ATOMIC_RELAXED, __HIP_MEMORY_SCOPE_AGENT);
}
__device__ __forceinline__ void ast8(ull* p, ull v){
  __hip_atomic_store(p, v, __ATOMIC_RELAXED, __HIP_MEMORY_SCOPE_AGENT);
}
__device__ __forceinline__ void asti(int* p, int v){
  __hip_atomic_store(p, v, __ATOMIC_RELAXED, __HIP_MEMORY_SCOPE_AGENT);
}
// {tag, 2 x bf16} in one 8B atom
__device__ __forceinline__ ull pack2b(float he, float ho, unsigned tag){
  unsigned lo = (unsigned)f2bf(he) | ((unsigned)f2bf(ho) << 16);
  return ((ull)tag << 32) | (ull)lo;
}

// ---------- prep kernels ----------

__global__ void k_embed_cvt(const float* __restrict__ e, unsigned short* __restrict__ ebf){
  long i = ((long)blockIdx.x * 256 + threadIdx.x) * 4;
  float4 v = *(const float4*)(e + i);
  ushort4 o;
  o.x = f2bf(v.x); o.y = f2bf(v.y); o.z = f2bf(v.z); o.w = f2bf(v.w);
  *(ushort4*)(ebf + i) = o;
}

__global__ void k_prep_misc(const float* __restrict__ b_ih2, const float* __restrict__ b_hh2,
                            float* __restrict__ b2c, ull* __restrict__ h1tag0,
                            ull* __restrict__ h2tag0, unsigned short* __restrict__ h2bf0,
                            int* __restrict__ done){
  int i = blockIdx.x * 256 + threadIdx.x;   // 8192 threads
  if(i < 4096){ h1tag0[i] = 0ull; h2tag0[i] = 0ull; }
  h2bf0[i] = 0;
  if(i < 2048){ b2c[i] = b_ih2[i] + b_hh2[i]; }
  if(i < 4096){ done[i] = 0; }
}

__global__ void k_a1const(const int* __restrict__ words, const float* __restrict__ embed,
                          const float* __restrict__ w_ih1, const float* __restrict__ b_ih1,
                          const float* __restrict__ b_hh1, float* __restrict__ a1c){
  int bb = threadIdx.x & 15, jj = threadIdx.x >> 4;
  int j = blockIdx.x * 16 + jj;
  const float* x0 = embed + (long)words[bb * 256] * 512;
  const float* wr = w_ih1 + (long)j * 1024;
  float acc = 0.f;
  for(int k = 0; k < 512; k += 4){
    float4 a = *(const float4*)(x0 + k);
    float4 b = *(const float4*)(wr + k);
    acc += a.x*b.x + a.y*b.y + a.z*b.z + a.w*b.w;
  }
  a1c[bb * 2048 + j] = acc + b_ih1[j] + b_hh1[j];
}

// ---------- recurrent kernel: MFMA gates, VGPR-resident W-frags, tagged exchange ----------
// 256 blocks x 4 waves. Per block per step: one 16x16 (MxN) gates GEMM, K split over waves,
// mfma_f32_16x16x32_bf16. B-frags (weights) preloaded to VGPRs once. h staged to LDS as
// bf16 A-rows, XOR-swizzled (2-way bank = free). 2 barriers/step. Wire {tag,2xbf16}.
__global__ void __launch_bounds__(256) k_recur(
    const float* __restrict__ w_hh1, const float* __restrict__ w_ih2, const float* __restrict__ w_hh2,
    const float* __restrict__ a1c, const float* __restrict__ b2c,
    ull* __restrict__ h1tag, ull* __restrict__ h2tag, unsigned short* __restrict__ h2bf,
    int* done){
  __shared__ unsigned A32[9216];          // 36KB: stage (L1 16KB / L2 32KB) + 4KB prt
  int* prog2 = done + 2048;               // L2 progress watermark, flag i at [i*16]
  const int bl = blockIdx.x, tid = threadIdx.x;
  const int l = tid & 63, w = tid >> 6;
  const bool isL1 = (bl < 128);
  const int ubase = (isL1 ? bl : bl - 128) * 4;
  const int col = l & 15;                  // gate-col of this lane (N index)
  const int arow = l & 15;                 // A-row (batch) of this lane (M index)
  const int kq = l >> 4;                   // k-subchunk 0..3 within an MFMA
  unsigned short* A16 = (unsigned short*)A32;
  float* prt = (float*)(A32 + (isL1 ? 4096 : 8192));   // 4x256 floats

  // ---- preload B fragments (weights) into VGPRs, bf16 ----
  short8 bw[8];
  {
    const int gg = col >> 2, uu = col & 3;
    const long wrow = (long)(gg * 512 + ubase + uu);
    if(isL1){
      #pragma unroll
      for(int i = 0; i < 4; ++i){
        int kk = w * 128 + i * 32 + kq * 8;
        const float* p = w_hh1 + wrow * 512 + kk;
        float4 x = *(const float4*)p, y = *(const float4*)(p + 4);
        short8 fr;
        fr[0]=(short)f2bf(x.x); fr[1]=(short)f2bf(x.y); fr[2]=(short)f2bf(x.z); fr[3]=(short)f2bf(x.w);
        fr[4]=(short)f2bf(y.x); fr[5]=(short)f2bf(y.y); fr[6]=(short)f2bf(y.z); fr[7]=(short)f2bf(y.w);
        bw[i] = fr;
      }
    } else {
      #pragma unroll
      for(int i = 0; i < 8; ++i){
        int kk = w * 256 + i * 32 + kq * 8;
        const float* p = (kk < 512) ? (w_ih2 + wrow * 512 + kk)
                                    : (w_hh2 + wrow * 512 + (kk - 512));
        float4 x = *(const float4*)p, y = *(const float4*)(p + 4);
        short8 fr;
        fr[0]=(short)f2bf(x.x); fr[1]=(short)f2bf(x.y); fr[2]=(short)f2bf(x.z); fr[3]=(short)f2bf(x.w);
        fr[4]=(short)f2bf(y.x); fr[5]=(short)f2bf(y.y); fr[6]=(short)f2bf(y.z); fr[7]=(short)f2bf(y.w);
        bw[i] = fr;
      }
    }
  }
  // ---- finalizer (wave 0, 64 threads): bias + cell state ----
  float ag[4] = {0.f, 0.f, 0.f, 0.f};
  float cst = 0.f;
  const int fb = tid >> 2, fu = tid & 3;   // valid for tid<64
  if(tid < 64){
    #pragma unroll
    for(int g = 0; g < 4; ++g)
      ag[g] = isL1 ? a1c[fb * 2048 + g * 512 + ubase + fu] : b2c[g * 512 + ubase + fu];
  }

  for(int s = 1; s <= 255; ++s){
    if(isL1){
      if(((s & 15) == 1) && s > 48 && tid < 64){
        for(;;){
          int ok = (aldr(prog2 + tid * 16) >= s - 40) & (aldr(prog2 + (64 + tid) * 16) >= s - 40);
          if(__all(ok)) break;
          __builtin_amdgcn_s_sleep(1);
        }
      }
      // ---- spin-stage h1(s-1) into bf16 A-rows [16][512] ----
      {
        const ull* src = h1tag + ((s - 1) & 63) * 4096;
        const unsigned want = (unsigned)(s - 1);
        ull v[16];
        #pragma unroll
        for(int j = 0; j < 16; ++j) v[j] = ald8(src + tid + 256 * j);
        for(;;){
          bool bad = false;
          #pragma unroll
          for(int j = 0; j < 16; ++j)
            if((unsigned)(v[j] >> 32) != want){ v[j] = ald8(src + tid + 256 * j); bad = true; }
          if(!bad) break;
        }
        #pragma unroll
        for(int j = 0; j < 16; ++j){
          int wd = tid + 256 * j, b = wd >> 8, pr = wd & 255;
          A32[b * 256 + (((pr >> 2) ^ (b & 7)) << 2) + (pr & 3)] = (unsigned)v[j];
        }
      }
      __syncthreads();                    // B1: stage -> MFMA
      f32x4 acc = {0.f, 0.f, 0.f, 0.f};
      #pragma unroll
      for(int i = 0; i < 4; ++i){
        int k8 = w * 16 + i * 4 + kq;
        const short8* ap = (const short8*)(A16 + arow * 512 + ((k8 ^ (arow & 7)) << 3));
        acc = __builtin_amdgcn_mfma_f32_16x16x32_bf16(*ap, bw[i], acc, 0, 0, 0);
      }
      *(f32x4*)(prt + w * 256 + col * 16 + (kq << 2)) = acc;
      __syncthreads();                    // B2: partials -> gates
      if(tid < 64){
        float g4[4];
        #pragma unroll
        for(int g = 0; g < 4; ++g){
          int c = (g * 4 + fu) * 16 + fb;
          g4[g] = ag[g] + prt[c] + prt[256 + c] + prt[512 + c] + prt[768 + c];
        }
        cst = sigm(g4[1]) * cst + sigm(g4[0]) * tanhf(g4[2]);
        float h = sigm(g4[3]) * tanhf(cst);
        float hn = __shfl(h, tid + 1);
        if((fu & 1) == 0)
          ast8(h1tag + (s & 63) * 4096 + fb * 256 + bl * 2 + (fu >> 1), pack2b(h, hn, (unsigned)s));
      }
      // stage/prt WAR protected by B1/B2 of the next iteration (disjoint regions)
    } else {
      // ---- L2: spin both rings, stage [h1(s) | h2(s-1)] as bf16 A-rows [16][1024] ----
      const ull* s1 = h1tag + (s & 63) * 4096;
      const ull* s2 = h2tag + ((s - 1) & 63) * 4096;
      const unsigned w1 = (unsigned)s, w2 = (unsigned)(s - 1);
      ull v1[16], v2[16];
      #pragma unroll
      for(int j = 0; j < 16; ++j) v1[j] = ald8(s1 + tid + 256 * j);
      #pragma unroll
      for(int j = 0; j < 16; ++j) v2[j] = ald8(s2 + tid + 256 * j);
      for(;;){
        bool bad = false;
        #pragma unroll
        for(int j = 0; j < 16; ++j)
          if((unsigned)(v1[j] >> 32) != w1){ v1[j] = ald8(s1 + tid + 256 * j); bad = true; }
        if(!bad) break;
      }
      for(;;){
        bool bad = false;
        #pragma unroll
        for(int j = 0; j < 16; ++j)
          if((unsigned)(v2[j] >> 32) != w2){ v2[j] = ald8(s2 + tid + 256 * j); bad = true; }
        if(!bad) break;
      }
      #pragma unroll
      for(int j = 0; j < 16; ++j){
        int wd = tid + 256 * j, b = wd >> 8, pr = wd & 255;
        int sw = (((pr >> 2) ^ (b & 7)) << 2) + (pr & 3);
        A32[b * 512 + sw] = (unsigned)v1[j];
        A32[b * 512 + 256 + sw] = (unsigned)v2[j];
      }
      __syncthreads();                    // B1
      f32x4 acc = {0.f, 0.f, 0.f, 0.f};
      #pragma unroll
      for(int i = 0; i < 8; ++i){
        int k8 = w * 32 + i * 4 + kq;
        const short8* ap = (const short8*)(A16 + arow * 1024 + ((k8 ^ (arow & 7)) << 3));
        acc = __builtin_amdgcn_mfma_f32_16x16x32_bf16(*ap, bw[i], acc, 0, 0, 0);
      }
      *(f32x4*)(prt + w * 256 + col * 16 + (kq << 2)) = acc;
      __syncthreads();                    // B2
      if(tid < 64){
        float g4[4];
        #pragma unroll
        for(int g = 0; g < 4; ++g){
          int c = (g * 4 + fu) * 16 + fb;
          g4[g] = ag[g] + prt[c] + prt[256 + c] + prt[512 + c] + prt[768 + c];
        }
        cst = sigm(g4[1]) * cst + sigm(g4[0]) * tanhf(g4[2]);
        float h = sigm(g4[3]) * tanhf(cst);
        float hn = __shfl(h, tid + 1);
        if((fu & 1) == 0)
          ast8(h2tag + (s & 63) * 4096 + fb * 256 + (bl - 128) * 2 + (fu >> 1),
               pack2b(h, hn, (unsigned)s));
        h2bf[((long)s * 16 + fb) * 512 + ubase + fu] = f2bf(h);
      }
      if(tid == 0) asti(prog2 + (bl - 128) * 16, s);
    }
  }
}

// ---------- projection GEMM (unchanged, passing) ----------
__global__ void __launch_bounds__(256, 2) k_proj(const unsigned short* __restrict__ A,
                                                 const unsigned short* __restrict__ Bm,
                                                 const float* __restrict__ fc_b,
                                                 float* __restrict__ out){
  __shared__ __align__(16) unsigned short As[4096];   // [128][32]
  __shared__ __align__(16) unsigned short Bs[4096];   // [128][32]
  const int tid = threadIdx.x;
  const int lane = tid & 63, w = tid >> 6;
  const int wr = w >> 1, wc = w & 1;
  const long mbase = (long)blockIdx.y * 128;
  const long nbase = (long)blockIdx.x * 128;
  f32x4 acc[4][4] = {};

  const int lrow = lane >> 2;
  const int lcol = (lane & 3) * 8;
  for(int kt = 0; kt < 16; ++kt){
    #pragma unroll
    for(int r = 0; r < 2; ++r){
      const unsigned short* ga = A  + (mbase + r*64 + w*16 + lrow) * 512 + kt*32 + lcol;
      __builtin_amdgcn_global_load_lds((const __attribute__((address_space(1))) void*)ga,
          (__attribute__((address_space(3))) void*)((char*)As + r*4096 + w*1024), 16, 0, 0);
      const unsigned short* gb = Bm + (nbase + r*64 + w*16 + lrow) * 512 + kt*32 + lcol;
      __builtin_amdgcn_global_load_lds((const __attribute__((address_space(1))) void*)gb,
          (__attribute__((address_space(3))) void*)((char*)Bs + r*4096 + w*1024), 16, 0, 0);
    }
    __syncthreads();
    short8 af[4], bf[4];
    const int kro = (lane >> 4) * 8;
    #pragma unroll
    for(int m = 0; m < 4; ++m){
      af[m] = *(const short8*)(As + (wr*64 + m*16 + (lane & 15)) * 32 + kro);
      bf[m] = *(const short8*)(Bs + (wc*64 + m*16 + (lane & 15)) * 32 + kro);
    }
    #pragma unroll
    for(int m = 0; m < 4; ++m){
      #pragma unroll
      for(int n = 0; n < 4; ++n){
        acc[m][n] = __builtin_amdgcn_mfma_f32_16x16x32_bf16(af[m], bf[n], acc[m][n], 0, 0, 0);
      }
    }
    __syncthreads();
  }
  const int crow0 = (lane >> 4) * 4;
  const int ccol = lane & 15;
  float fb[4];
  #pragma unroll
  for(int n = 0; n < 4; ++n) fb[n] = fc_b[nbase + wc*64 + n*16 + ccol];
  #pragma unroll
  for(int m = 0; m < 4; ++m){
    #pragma unroll
    for(int j = 0; j < 4; ++j){
      long rr = mbase + wr*64 + m*16 + crow0 + j;
      int t = (int)(rr >> 4), b = (int)(rr & 15);
      float* orow = out + ((long)b * 256 + t) * 32000;
      #pragma unroll
      for(int n = 0; n < 4; ++n){
        float v = (t == 0) ? 0.f : (acc[m][n][j] + fb[n]);
        orow[nbase + wc*64 + n*16 + ccol] = v;
      }
    }
  }
}

extern "C" void kernel_launch(void* const* d_in, const int* in_sizes, int n_in,
                              void* d_out, int out_size, void* d_ws, size_t ws_size,
                              hipStream_t stream){
  const int*   words = (const int*)  d_in[0];
  const float* embed = (const float*)d_in[1];
  const float* fc_b  = (const float*)d_in[2];
  const float* w_ih1 = (const float*)d_in[3];
  const float* w_hh1 = (const float*)d_in[4];
  const float* b_ih1 = (const float*)d_in[5];
  const float* b_hh1 = (const float*)d_in[6];
  const float* w_ih2 = (const float*)d_in[7];
  const float* w_hh2 = (const float*)d_in[8];
  const float* b_ih2 = (const float*)d_in[9];
  const float* b_hh2 = (const float*)d_in[10];
  float* out = (float*)d_out;
  char* ws = (char*)d_ws;

  unsigned short* embed_bf = (unsigned short*)(ws + 0);          // 32,768,000 B
  unsigned short* h2bf     = (unsigned short*)(ws + 32768000);   //  4,194,304 B (4096x512)
  ull* h1tag = (ull*)(ws + 36962304);                            //  2,097,152 B (64 x 4096 ull)
  ull* h2tag = (ull*)(ws + 39059456);                            //  2,097,152 B
  float* a1c = (float*)(ws + 41156608);                          //    131,072 B (16x2048)
  float* b2c = (float*)(ws + 41287680);                          //      8,192 B
  int*   done = (int*) (ws + 41295872);                          //     16,384 B (4096 ints)
  // total 41,312,256 B

  k_embed_cvt<<<16000, 256, 0, stream>>>(embed, embed_bf);
  k_prep_misc<<<32, 256, 0, stream>>>(b_ih2, b_hh2, b2c, h1tag, h2tag, h2bf, done);
  k_a1const<<<128, 256, 0, stream>>>(words, embed, w_ih1, b_ih1, b_hh1, a1c);

  // k_recur needs only de-facto co-residency (no grid.sync). Coop launch when the
  // runtime accepts it; otherwise plain launch (the R3..R9 silent-failure fix).
  void* args[9];
  args[0] = (void*)&w_hh1; args[1] = (void*)&w_ih2; args[2] = (void*)&w_hh2;
  args[3] = (void*)&a1c;   args[4] = (void*)&b2c;
  args[5] = (void*)&h1tag; args[6] = (void*)&h2tag; args[7] = (void*)&h2bf;
  args[8] = (void*)&done;
  hipError_t ce = hipLaunchCooperativeKernel((const void*)k_recur, dim3(256), dim3(256),
                                             args, 0, stream);
  if(ce != hipSuccess){
    k_recur<<<dim3(256), dim3(256), 0, stream>>>(w_hh1, w_ih2, w_hh2, a1c, b2c,
                                                 h1tag, h2tag, h2bf, done);
  }

  k_proj<<<dim3(250, 32), 256, 0, stream>>>(h2bf, embed_bf, fc_b, out);
}

// Round 17
// 1131.158 us; speedup vs baseline: 1.7826x; 1.5645x over previous
//
#include <hip/hip_runtime.h>

typedef __attribute__((ext_vector_type(8))) short short8;
typedef __attribute__((ext_vector_type(4))) float f32x4;
typedef unsigned long long ull;

__device__ __forceinline__ unsigned short f2bf(float f){
  unsigned u = __float_as_uint(f);
  u += 0x7FFFu + ((u >> 16) & 1u);
  return (unsigned short)(u >> 16);
}
__device__ __forceinline__ float sigm(float x){ return 1.f / (1.f + expf(-x)); }
__device__ __forceinline__ int aldr(const int* p){
  return __hip_atomic_load(p, __ATOMIC_RELAXED, __HIP_MEMORY_SCOPE_AGENT);
}
__device__ __forceinline__ ull ald8(const ull* p){
  return __hip_atomic_load(p, __ATOMIC_RELAXED, __HIP_MEMORY_SCOPE_AGENT);
}
__device__ __forceinline__ void ast8(ull* p, ull v){
  __hip_atomic_store(p, v, __ATOMIC_RELAXED, __HIP_MEMORY_SCOPE_AGENT);
}
__device__ __forceinline__ void asti(int* p, int v){
  __hip_atomic_store(p, v, __ATOMIC_RELAXED, __HIP_MEMORY_SCOPE_AGENT);
}
// {tag, 2 x bf16} in one 8B atom
__device__ __forceinline__ ull pack2b(float he, float ho, unsigned tag){
  unsigned lo = (unsigned)f2bf(he) | ((unsigned)f2bf(ho) << 16);
  return ((ull)tag << 32) | (ull)lo;
}
__device__ __forceinline__ short8 ld_bf16frag(const float* p){
  float4 x = *(const float4*)p, y = *(const float4*)(p + 4);
  short8 fr;
  fr[0]=(short)f2bf(x.x); fr[1]=(short)f2bf(x.y); fr[2]=(short)f2bf(x.z); fr[3]=(short)f2bf(x.w);
  fr[4]=(short)f2bf(y.x); fr[5]=(short)f2bf(y.y); fr[6]=(short)f2bf(y.z); fr[7]=(short)f2bf(y.w);
  return fr;
}

// ---------- prep kernels ----------

__global__ void k_embed_cvt(const float* __restrict__ e, unsigned short* __restrict__ ebf){
  long i = ((long)blockIdx.x * 256 + threadIdx.x) * 4;
  float4 v = *(const float4*)(e + i);
  ushort4 o;
  o.x = f2bf(v.x); o.y = f2bf(v.y); o.z = f2bf(v.z); o.w = f2bf(v.w);
  *(ushort4*)(ebf + i) = o;
}

__global__ void k_prep_misc(const float* __restrict__ b_ih2, const float* __restrict__ b_hh2,
                            float* __restrict__ b2c, ull* __restrict__ h1tag0,
                            ull* __restrict__ h2tag0, unsigned short* __restrict__ h2bf0,
                            int* __restrict__ done){
  int i = blockIdx.x * 256 + threadIdx.x;   // 8192 threads
  if(i < 4096){ h1tag0[i] = 0ull; h2tag0[i] = 0ull; }
  h2bf0[i] = 0;
  if(i < 2048){ b2c[i] = b_ih2[i] + b_hh2[i]; }
  if(i < 4096){ done[i] = 0; }
}

__global__ void k_a1const(const int* __restrict__ words, const float* __restrict__ embed,
                          const float* __restrict__ w_ih1, const float* __restrict__ b_ih1,
                          const float* __restrict__ b_hh1, float* __restrict__ a1c){
  int bb = threadIdx.x & 15, jj = threadIdx.x >> 4;
  int j = blockIdx.x * 16 + jj;
  const float* x0 = embed + (long)words[bb * 256] * 512;
  const float* wr = w_ih1 + (long)j * 1024;
  float acc = 0.f;
  for(int k = 0; k < 512; k += 4){
    float4 a = *(const float4*)(x0 + k);
    float4 b = *(const float4*)(wr + k);
    acc += a.x*b.x + a.y*b.y + a.z*b.z + a.w*b.w;
  }
  a1c[bb * 2048 + j] = acc + b_ih1[j] + b_hh1[j];
}

// ---------- recurrent kernel: MFMA gates, 64 blocks x 16 units, tagged exchange ----------
// bl<32: layer-1 (16 units, N=64, K=512). bl>=32: layer-2 (16 units, N=64, K=1024).
// B-frags in VGPRs; h staged to LDS bf16 A-rows (R16-proven swizzle); 2 barriers/step.
// 4x fewer exchange readers than R16 (64 x 32-64KB vs 256).
__global__ void __launch_bounds__(256, 1) k_recur(
    const float* __restrict__ w_hh1, const float* __restrict__ w_ih2, const float* __restrict__ w_hh2,
    const float* __restrict__ a1c, const float* __restrict__ b2c,
    ull* __restrict__ h1tag, ull* __restrict__ h2tag, unsigned short* __restrict__ h2bf,
    int* done){
  __shared__ unsigned A32[12288];         // 48KB: A-stage (16/32KB) + prt 16KB
  unsigned short* A16 = (unsigned short*)A32;
  int* prog2 = done + 2048;               // L2 progress watermark, flag i at [i*16]
  const int bl = blockIdx.x, tid = threadIdx.x;
  const int l = tid & 63, w = tid >> 6;
  const int lu = l & 15, kq = l >> 4;
  const bool isL1 = (bl < 32);
  const int blk = isL1 ? bl : bl - 32;
  const int ubase = blk * 16;
  const int fu = tid & 15, fb = tid >> 4;  // finalize mapping: all 256 threads, one (b,u)
  float ag[4];
  float cst = 0.f;
  #pragma unroll
  for(int g = 0; g < 4; ++g)
    ag[g] = isL1 ? a1c[fb * 2048 + g * 512 + ubase + fu] : b2c[g * 512 + ubase + fu];

  if(isL1){
    float* prt = (float*)(A32 + 4096);    // 16KB at [16KB..32KB)
    // ---- preload B frags: tile n = gate, 4 K-tiles per wave ----
    short8 bw[4][4];
    #pragma unroll
    for(int n = 0; n < 4; ++n){
      const long wrow = (long)(n * 512 + ubase + lu);
      #pragma unroll
      for(int i = 0; i < 4; ++i){
        int kk = w * 128 + i * 32 + kq * 8;
        bw[n][i] = ld_bf16frag(w_hh1 + wrow * 512 + kk);
      }
    }
    for(int s = 1; s <= 255; ++s){
      if(((s & 15) == 1) && s > 48 && tid < 64){
        for(;;){
          int ok = (tid < 32) ? (aldr(prog2 + tid * 16) >= s - 40) : 1;
          if(__all(ok)) break;
          __builtin_amdgcn_s_sleep(1);
        }
      }
      // ---- spin-stage h1(s-1) into bf16 A-rows [16][512] (R16-proven) ----
      {
        const ull* src = h1tag + ((s - 1) & 63) * 4096;
        const unsigned want = (unsigned)(s - 1);
        ull v[16];
        #pragma unroll
        for(int j = 0; j < 16; ++j) v[j] = ald8(src + tid + 256 * j);
        for(;;){
          bool bad = false;
          #pragma unroll
          for(int j = 0; j < 16; ++j)
            if((unsigned)(v[j] >> 32) != want){ v[j] = ald8(src + tid + 256 * j); bad = true; }
          if(!bad) break;
        }
        #pragma unroll
        for(int j = 0; j < 16; ++j){
          int wd = tid + 256 * j, b = wd >> 8, pr = wd & 255;
          A32[b * 256 + (((pr >> 2) ^ (b & 7)) << 2) + (pr & 3)] = (unsigned)v[j];
        }
      }
      __syncthreads();                    // B1: stage -> MFMA
      f32x4 acc[4] = {};
      #pragma unroll
      for(int i = 0; i < 4; ++i){
        int k8 = w * 16 + i * 4 + kq;
        const short8* ap = (const short8*)(A16 + lu * 512 + ((k8 ^ (lu & 7)) << 3));
        #pragma unroll
        for(int n = 0; n < 4; ++n)
          acc[n] = __builtin_amdgcn_mfma_f32_16x16x32_bf16(*ap, bw[n][i], acc[n], 0, 0, 0);
      }
      #pragma unroll
      for(int n = 0; n < 4; ++n)
        #pragma unroll
        for(int j = 0; j < 4; ++j)
          prt[w * 1024 + n * 256 + (kq * 4 + j) * 16 + lu] = acc[n][j];
      __syncthreads();                    // B2: partials -> gates
      {
        float g4[4];
        #pragma unroll
        for(int g = 0; g < 4; ++g){
          int c = g * 256 + fb * 16 + fu;
          g4[g] = ag[g] + prt[c] + prt[1024 + c] + prt[2048 + c] + prt[3072 + c];
        }
        cst = sigm(g4[1]) * cst + sigm(g4[0]) * tanhf(g4[2]);
        float h = sigm(g4[3]) * tanhf(cst);
        float hn = __shfl(h, tid + 1);
        if((fu & 1) == 0)
          ast8(h1tag + (s & 63) * 4096 + fb * 256 + blk * 8 + (fu >> 1), pack2b(h, hn, (unsigned)s));
      }
      // WAR protected by next iteration's B1/B2 (A and prt disjoint)
    }
  } else {
    float* prt = (float*)(A32 + 8192);    // 16KB at [32KB..48KB)
    // ---- preload B frags: 8 K-tiles per wave, K = [h1 | h2] ----
    short8 bw[4][8];
    #pragma unroll
    for(int n = 0; n < 4; ++n){
      const long wrow = (long)(n * 512 + ubase + lu);
      #pragma unroll
      for(int i = 0; i < 8; ++i){
        int kk = w * 256 + i * 32 + kq * 8;
        const float* p = (kk < 512) ? (w_ih2 + wrow * 512 + kk)
                                    : (w_hh2 + wrow * 512 + (kk - 512));
        bw[n][i] = ld_bf16frag(p);
      }
    }
    for(int s = 1; s <= 255; ++s){
      // ---- spin both rings, stage [h1(s) | h2(s-1)] into [16][1024] (R16-proven) ----
      const ull* s1 = h1tag + (s & 63) * 4096;
      const ull* s2 = h2tag + ((s - 1) & 63) * 4096;
      const unsigned w1 = (unsigned)s, w2 = (unsigned)(s - 1);
      ull v1[16], v2[16];
      #pragma unroll
      for(int j = 0; j < 16; ++j) v1[j] = ald8(s1 + tid + 256 * j);
      #pragma unroll
      for(int j = 0; j < 16; ++j) v2[j] = ald8(s2 + tid + 256 * j);
      for(;;){
        bool bad = false;
        #pragma unroll
        for(int j = 0; j < 16; ++j)
          if((unsigned)(v1[j] >> 32) != w1){ v1[j] = ald8(s1 + tid + 256 * j); bad = true; }
        if(!bad) break;
      }
      for(;;){
        bool bad = false;
        #pragma unroll
        for(int j = 0; j < 16; ++j)
          if((unsigned)(v2[j] >> 32) != w2){ v2[j] = ald8(s2 + tid + 256 * j); bad = true; }
        if(!bad) break;
      }
      #pragma unroll
      for(int j = 0; j < 16; ++j){
        int wd = tid + 256 * j, b = wd >> 8, pr = wd & 255;
        int sw = (((pr >> 2) ^ (b & 7)) << 2) + (pr & 3);
        A32[b * 512 + sw] = (unsigned)v1[j];
        A32[b * 512 + 256 + sw] = (unsigned)v2[j];
      }
      __syncthreads();                    // B1
      f32x4 acc[4] = {};
      #pragma unroll
      for(int i = 0; i < 8; ++i){
        int k8 = w * 32 + i * 4 + kq;
        const short8* ap = (const short8*)(A16 + lu * 1024 + ((k8 ^ (lu & 7)) << 3));
        #pragma unroll
        for(int n = 0; n < 4; ++n)
          acc[n] = __builtin_amdgcn_mfma_f32_16x16x32_bf16(*ap, bw[n][i], acc[n], 0, 0, 0);
      }
      #pragma unroll
      for(int n = 0; n < 4; ++n)
        #pragma unroll
        for(int j = 0; j < 4; ++j)
          prt[w * 1024 + n * 256 + (kq * 4 + j) * 16 + lu] = acc[n][j];
      __syncthreads();                    // B2
      {
        float g4[4];
        #pragma unroll
        for(int g = 0; g < 4; ++g){
          int c = g * 256 + fb * 16 + fu;
          g4[g] = ag[g] + prt[c] + prt[1024 + c] + prt[2048 + c] + prt[3072 + c];
        }
        cst = sigm(g4[1]) * cst + sigm(g4[0]) * tanhf(g4[2]);
        float h = sigm(g4[3]) * tanhf(cst);
        float hn = __shfl(h, tid + 1);
        if((fu & 1) == 0)
          ast8(h2tag + (s & 63) * 4096 + fb * 256 + blk * 8 + (fu >> 1), pack2b(h, hn, (unsigned)s));
        h2bf[((long)s * 16 + fb) * 512 + ubase + fu] = f2bf(h);
      }
      if(tid == 0) asti(prog2 + blk * 16, s);
    }
  }
}

// ---------- projection GEMM (unchanged, passing) ----------
__global__ void __launch_bounds__(256, 2) k_proj(const unsigned short* __restrict__ A,
                                                 const unsigned short* __restrict__ Bm,
                                                 const float* __restrict__ fc_b,
                                                 float* __restrict__ out){
  __shared__ __align__(16) unsigned short As[4096];   // [128][32]
  __shared__ __align__(16) unsigned short Bs[4096];   // [128][32]
  const int tid = threadIdx.x;
  const int lane = tid & 63, w = tid >> 6;
  const int wr = w >> 1, wc = w & 1;
  const long mbase = (long)blockIdx.y * 128;
  const long nbase = (long)blockIdx.x * 128;
  f32x4 acc[4][4] = {};

  const int lrow = lane >> 2;
  const int lcol = (lane & 3) * 8;
  for(int kt = 0; kt < 16; ++kt){
    #pragma unroll
    for(int r = 0; r < 2; ++r){
      const unsigned short* ga = A  + (mbase + r*64 + w*16 + lrow) * 512 + kt*32 + lcol;
      __builtin_amdgcn_global_load_lds((const __attribute__((address_space(1))) void*)ga,
          (__attribute__((address_space(3))) void*)((char*)As + r*4096 + w*1024), 16, 0, 0);
      const unsigned short* gb = Bm + (nbase + r*64 + w*16 + lrow) * 512 + kt*32 + lcol;
      __builtin_amdgcn_global_load_lds((const __attribute__((address_space(1))) void*)gb,
          (__attribute__((address_space(3))) void*)((char*)Bs + r*4096 + w*1024), 16, 0, 0);
    }
    __syncthreads();
    short8 af[4], bf[4];
    const int kro = (lane >> 4) * 8;
    #pragma unroll
    for(int m = 0; m < 4; ++m){
      af[m] = *(const short8*)(As + (wr*64 + m*16 + (lane & 15)) * 32 + kro);
      bf[m] = *(const short8*)(Bs + (wc*64 + m*16 + (lane & 15)) * 32 + kro);
    }
    #pragma unroll
    for(int m = 0; m < 4; ++m){
      #pragma unroll
      for(int n = 0; n < 4; ++n){
        acc[m][n] = __builtin_amdgcn_mfma_f32_16x16x32_bf16(af[m], bf[n], acc[m][n], 0, 0, 0);
      }
    }
    __syncthreads();
  }
  const int crow0 = (lane >> 4) * 4;
  const int ccol = lane & 15;
  float fb[4];
  #pragma unroll
  for(int n = 0; n < 4; ++n) fb[n] = fc_b[nbase + wc*64 + n*16 + ccol];
  #pragma unroll
  for(int m = 0; m < 4; ++m){
    #pragma unroll
    for(int j = 0; j < 4; ++j){
      long rr = mbase + wr*64 + m*16 + crow0 + j;
      int t = (int)(rr >> 4), b = (int)(rr & 15);
      float* orow = out + ((long)b * 256 + t) * 32000;
      #pragma unroll
      for(int n = 0; n < 4; ++n){
        float v = (t == 0) ? 0.f : (acc[m][n][j] + fb[n]);
        orow[nbase + wc*64 + n*16 + ccol] = v;
      }
    }
  }
}

extern "C" void kernel_launch(void* const* d_in, const int* in_sizes, int n_in,
                              void* d_out, int out_size, void* d_ws, size_t ws_size,
                              hipStream_t stream){
  const int*   words = (const int*)  d_in[0];
  const float* embed = (const float*)d_in[1];
  const float* fc_b  = (const float*)d_in[2];
  const float* w_ih1 = (const float*)d_in[3];
  const float* w_hh1 = (const float*)d_in[4];
  const float* b_ih1 = (const float*)d_in[5];
  const float* b_hh1 = (const float*)d_in[6];
  const float* w_ih2 = (const float*)d_in[7];
  const float* w_hh2 = (const float*)d_in[8];
  const float* b_ih2 = (const float*)d_in[9];
  const float* b_hh2 = (const float*)d_in[10];
  float* out = (float*)d_out;
  char* ws = (char*)d_ws;

  unsigned short* embed_bf = (unsigned short*)(ws + 0);          // 32,768,000 B
  unsigned short* h2bf     = (unsigned short*)(ws + 32768000);   //  4,194,304 B (4096x512)
  ull* h1tag = (ull*)(ws + 36962304);                            //  2,097,152 B (64 x 4096 ull)
  ull* h2tag = (ull*)(ws + 39059456);                            //  2,097,152 B
  float* a1c = (float*)(ws + 41156608);                          //    131,072 B (16x2048)
  float* b2c = (float*)(ws + 41287680);                          //      8,192 B
  int*   done = (int*) (ws + 41295872);                          //     16,384 B (4096 ints)
  // total 41,312,256 B

  k_embed_cvt<<<16000, 256, 0, stream>>>(embed, embed_bf);
  k_prep_misc<<<32, 256, 0, stream>>>(b_ih2, b_hh2, b2c, h1tag, h2tag, h2bf, done);
  k_a1const<<<128, 256, 0, stream>>>(words, embed, w_ih1, b_ih1, b_hh1, a1c);

  // k_recur needs only de-facto co-residency (no grid.sync). Coop launch when the
  // runtime accepts it; otherwise plain launch (the R3..R9 silent-failure fix).
  void* args[9];
  args[0] = (void*)&w_hh1; args[1] = (void*)&w_ih2; args[2] = (void*)&w_hh2;
  args[3] = (void*)&a1c;   args[4] = (void*)&b2c;
  args[5] = (void*)&h1tag; args[6] = (void*)&h2tag; args[7] = (void*)&h2bf;
  args[8] = (void*)&done;
  hipError_t ce = hipLaunchCooperativeKernel((const void*)k_recur, dim3(64), dim3(256),
                                             args, 0, stream);
  if(ce != hipSuccess){
    k_recur<<<dim3(64), dim3(256), 0, stream>>>(w_hh1, w_ih2, w_hh2, a1c, b2c,
                                                h1tag, h2tag, h2bf, done);
  }

  k_proj<<<dim3(250, 32), 256, 0, stream>>>(h2bf, embed_bf, fc_b, out);
}

// Round 18
// 967.965 us; speedup vs baseline: 2.0831x; 1.1686x over previous
//
#include <hip/hip_runtime.h>

typedef __attribute__((ext_vector_type(8))) short short8;
typedef __attribute__((ext_vector_type(4))) float f32x4;
typedef unsigned long long ull;

__device__ __forceinline__ unsigned short f2bf(float f){
  unsigned u = __float_as_uint(f);
  u += 0x7FFFu + ((u >> 16) & 1u);
  return (unsigned short)(u >> 16);
}
__device__ __forceinline__ float sigm(float x){ return 1.f / (1.f + expf(-x)); }
__device__ __forceinline__ int aldr(const int* p){
  return __hip_atomic_load(p, __ATOMIC_RELAXED, __HIP_MEMORY_SCOPE_AGENT);
}
__device__ __forceinline__ ull ald8(const ull* p){
  return __hip_atomic_load(p, __ATOMIC_RELAXED, __HIP_MEMORY_SCOPE_AGENT);
}
__device__ __forceinline__ void ast8(ull* p, ull v){
  __hip_atomic_store(p, v, __ATOMIC_RELAXED, __HIP_MEMORY_SCOPE_AGENT);
}
__device__ __forceinline__ void asti(int* p, int v){
  __hip_atomic_store(p, v, __ATOMIC_RELAXED, __HIP_MEMORY_SCOPE_AGENT);
}
// {tag, 2 x bf16} in one 8B atom
__device__ __forceinline__ ull pack2b(float he, float ho, unsigned tag){
  unsigned lo = (unsigned)f2bf(he) | ((unsigned)f2bf(ho) << 16);
  return ((ull)tag << 32) | (ull)lo;
}
__device__ __forceinline__ short8 ld_bf16frag(const float* p){
  float4 x = *(const float4*)p, y = *(const float4*)(p + 4);
  short8 fr;
  fr[0]=(short)f2bf(x.x); fr[1]=(short)f2bf(x.y); fr[2]=(short)f2bf(x.z); fr[3]=(short)f2bf(x.w);
  fr[4]=(short)f2bf(y.x); fr[5]=(short)f2bf(y.y); fr[6]=(short)f2bf(y.z); fr[7]=(short)f2bf(y.w);
  return fr;
}

// ---------- prep kernels ----------

__global__ void k_embed_cvt(const float* __restrict__ e, unsigned short* __restrict__ ebf){
  long i = ((long)blockIdx.x * 256 + threadIdx.x) * 4;
  float4 v = *(const float4*)(e + i);
  ushort4 o;
  o.x = f2bf(v.x); o.y = f2bf(v.y); o.z = f2bf(v.z); o.w = f2bf(v.w);
  *(ushort4*)(ebf + i) = o;
}

__global__ void k_prep_misc(const float* __restrict__ b_ih2, const float* __restrict__ b_hh2,
                            float* __restrict__ b2c, ull* __restrict__ h1tag0,
                            ull* __restrict__ h2tag0, unsigned short* __restrict__ h2bf0,
                            int* __restrict__ done){
  int i = blockIdx.x * 256 + threadIdx.x;   // 8192 threads
  if(i < 4096){ h1tag0[i] = 0ull; h2tag0[i] = 0ull; }
  h2bf0[i] = 0;
  if(i < 2048){ b2c[i] = b_ih2[i] + b_hh2[i]; }
  if(i < 4096){ done[i] = 0; }
}

__global__ void k_a1const(const int* __restrict__ words, const float* __restrict__ embed,
                          const float* __restrict__ w_ih1, const float* __restrict__ b_ih1,
                          const float* __restrict__ b_hh1, float* __restrict__ a1c){
  int bb = threadIdx.x & 15, jj = threadIdx.x >> 4;
  int j = blockIdx.x * 16 + jj;
  const float* x0 = embed + (long)words[bb * 256] * 512;
  const float* wr = w_ih1 + (long)j * 1024;
  float acc = 0.f;
  for(int k = 0; k < 512; k += 4){
    float4 a = *(const float4*)(x0 + k);
    float4 b = *(const float4*)(wr + k);
    acc += a.x*b.x + a.y*b.y + a.z*b.z + a.w*b.w;
  }
  a1c[bb * 2048 + j] = acc + b_ih1[j] + b_hh1[j];
}

// ---------- progress-gated projection worker (shared by all blocks) ----------
// Tiles 8000 = 32 mb x 250 nb; tile tix gated on all 32 L2 recur blocks having
// published prog2 >= tEnd(mb), then acquire-fence so h2bf (L3, sc-written) is fresh.
__device__ __forceinline__ void proj_worker(unsigned* A32, const unsigned short* Ah,
    const unsigned short* Bm, const float* __restrict__ fc_b, float* __restrict__ out,
    int* prog2, int* ctr, int tid){
  unsigned short* As = (unsigned short*)A32;          // 8KB [0..2048) u32
  unsigned short* Bs = (unsigned short*)A32 + 4096;   // 8KB [2048..4096) u32
  int* sbox = (int*)(A32 + 4096);
  const int lane = tid & 63, w = tid >> 6;
  const int wr = w >> 1, wc = w & 1;
  const int lrow = lane >> 2;
  const int lcol = (lane & 3) * 8;
  int curgate = -1;
  for(;;){
    if(tid == 0)
      *sbox = __hip_atomic_fetch_add(ctr, 1, __ATOMIC_RELAXED, __HIP_MEMORY_SCOPE_AGENT);
    __syncthreads();
    int tix = *sbox;
    __syncthreads();
    if(tix >= 8000) break;
    int mb = tix / 250, nb = tix - mb * 250;
    int tEnd = mb * 8 + 7;
    if(tEnd > curgate){
      if(tid < 64){
        for(;;){
          int ok = (tid < 32) ? (aldr(prog2 + tid * 16) >= tEnd) : 1;
          if(__all(ok)) break;
          __builtin_amdgcn_s_sleep(1);
        }
        __builtin_amdgcn_fence(__ATOMIC_ACQUIRE, "agent");   // h2bf fresh from L3
      }
      __syncthreads();
      curgate = tEnd;
    }
    const long mbase = (long)mb * 128;
    const long nbase = (long)nb * 128;
    f32x4 acc[4][4] = {};
    for(int kt = 0; kt < 16; ++kt){
      #pragma unroll
      for(int r = 0; r < 2; ++r){
        const unsigned short* ga = Ah + (mbase + r*64 + w*16 + lrow) * 512 + kt*32 + lcol;
        __builtin_amdgcn_global_load_lds((const __attribute__((address_space(1))) void*)ga,
            (__attribute__((address_space(3))) void*)((char*)As + r*4096 + w*1024), 16, 0, 0);
        const unsigned short* gb = Bm + (nbase + r*64 + w*16 + lrow) * 512 + kt*32 + lcol;
        __builtin_amdgcn_global_load_lds((const __attribute__((address_space(1))) void*)gb,
            (__attribute__((address_space(3))) void*)((char*)Bs + r*4096 + w*1024), 16, 0, 0);
      }
      __syncthreads();
      short8 af[4], bf[4];
      const int kro = (lane >> 4) * 8;
      #pragma unroll
      for(int m = 0; m < 4; ++m){
        af[m] = *(const short8*)(As + (wr*64 + m*16 + (lane & 15)) * 32 + kro);
        bf[m] = *(const short8*)(Bs + (wc*64 + m*16 + (lane & 15)) * 32 + kro);
      }
      #pragma unroll
      for(int m = 0; m < 4; ++m){
        #pragma unroll
        for(int n = 0; n < 4; ++n){
          acc[m][n] = __builtin_amdgcn_mfma_f32_16x16x32_bf16(af[m], bf[n], acc[m][n], 0, 0, 0);
        }
      }
      __syncthreads();
    }
    const int crow0 = (lane >> 4) * 4;
    const int ccol = lane & 15;
    float fb4[4];
    #pragma unroll
    for(int n = 0; n < 4; ++n) fb4[n] = fc_b[nbase + wc*64 + n*16 + ccol];
    #pragma unroll
    for(int m = 0; m < 4; ++m){
      #pragma unroll
      for(int j = 0; j < 4; ++j){
        long rr = mbase + wr*64 + m*16 + crow0 + j;
        int t = (int)(rr >> 4), b = (int)(rr & 15);
        float* orow = out + ((long)b * 256 + t) * 32000;
        #pragma unroll
        for(int n = 0; n < 4; ++n){
          float v = (t == 0) ? 0.f : (acc[m][n][j] + fb4[n]);
          orow[nbase + wc*64 + n*16 + ccol] = v;
        }
      }
    }
  }
}

// ---------- fused kernel: recurrence (blocks 0..63) + progress-gated projection ----------
// Recurrence identical to R17 (MFMA gates, VGPR B-frags, tagged bf16-pair exchange),
// except L2 writes h2bf via packed agent-scope u32 stores and publishes prog2 after a
// barrier (release). Blocks 64+ (and recur blocks when done) drain proj tiles.
__global__ void __launch_bounds__(256, 1) k_recur(
    const float* __restrict__ w_hh1, const float* __restrict__ w_ih2, const float* __restrict__ w_hh2,
    const float* __restrict__ a1c, const float* __restrict__ b2c,
    ull* __restrict__ h1tag, ull* __restrict__ h2tag, unsigned short* __restrict__ h2bf,
    int* done, const unsigned short* __restrict__ embed_bf,
    const float* __restrict__ fc_b, float* __restrict__ out){
  __shared__ unsigned A32[12288];         // 48KB
  unsigned short* A16 = (unsigned short*)A32;
  int* prog2 = done + 2048;               // L2 progress, flag i at [i*16]
  int* ctr   = done + 1600;               // proj tile counter
  const int bl = blockIdx.x, tid = threadIdx.x;
  const int l = tid & 63, w = tid >> 6;
  const int lu = l & 15, kq = l >> 4;
  const bool isL1 = (bl < 32);
  const int blk = isL1 ? bl : bl - 32;
  const int ubase = blk * 16;
  const int fu = tid & 15, fb = tid >> 4;

  if(bl < 64){
    float ag[4];
    float cst = 0.f;
    #pragma unroll
    for(int g = 0; g < 4; ++g)
      ag[g] = isL1 ? a1c[fb * 2048 + g * 512 + ubase + fu] : b2c[g * 512 + ubase + fu];

    if(isL1){
      float* prt = (float*)(A32 + 4096);    // 16KB at [16KB..32KB)
      short8 bw[4][4];
      #pragma unroll
      for(int n = 0; n < 4; ++n){
        const long wrow = (long)(n * 512 + ubase + lu);
        #pragma unroll
        for(int i = 0; i < 4; ++i){
          int kk = w * 128 + i * 32 + kq * 8;
          bw[n][i] = ld_bf16frag(w_hh1 + wrow * 512 + kk);
        }
      }
      for(int s = 1; s <= 255; ++s){
        if(((s & 15) == 1) && s > 48 && tid < 64){
          for(;;){
            int ok = (tid < 32) ? (aldr(prog2 + tid * 16) >= s - 40) : 1;
            if(__all(ok)) break;
            __builtin_amdgcn_s_sleep(1);
          }
        }
        { // spin-stage h1(s-1) -> bf16 A-rows [16][512]
          const ull* src = h1tag + ((s - 1) & 63) * 4096;
          const unsigned want = (unsigned)(s - 1);
          ull v[16];
          #pragma unroll
          for(int j = 0; j < 16; ++j) v[j] = ald8(src + tid + 256 * j);
          for(;;){
            bool bad = false;
            #pragma unroll
            for(int j = 0; j < 16; ++j)
              if((unsigned)(v[j] >> 32) != want){ v[j] = ald8(src + tid + 256 * j); bad = true; }
            if(!bad) break;
          }
          #pragma unroll
          for(int j = 0; j < 16; ++j){
            int wd = tid + 256 * j, b = wd >> 8, pr = wd & 255;
            A32[b * 256 + (((pr >> 2) ^ (b & 7)) << 2) + (pr & 3)] = (unsigned)v[j];
          }
        }
        __syncthreads();                    // B1
        f32x4 acc[4] = {};
        #pragma unroll
        for(int i = 0; i < 4; ++i){
          int k8 = w * 16 + i * 4 + kq;
          const short8* ap = (const short8*)(A16 + lu * 512 + ((k8 ^ (lu & 7)) << 3));
          #pragma unroll
          for(int n = 0; n < 4; ++n)
            acc[n] = __builtin_amdgcn_mfma_f32_16x16x32_bf16(*ap, bw[n][i], acc[n], 0, 0, 0);
        }
        #pragma unroll
        for(int n = 0; n < 4; ++n)
          #pragma unroll
          for(int j = 0; j < 4; ++j)
            prt[w * 1024 + n * 256 + (kq * 4 + j) * 16 + lu] = acc[n][j];
        __syncthreads();                    // B2
        {
          float g4[4];
          #pragma unroll
          for(int g = 0; g < 4; ++g){
            int c = g * 256 + fb * 16 + fu;
            g4[g] = ag[g] + prt[c] + prt[1024 + c] + prt[2048 + c] + prt[3072 + c];
          }
          cst = sigm(g4[1]) * cst + sigm(g4[0]) * tanhf(g4[2]);
          float h = sigm(g4[3]) * tanhf(cst);
          float hn = __shfl(h, tid + 1);
          if((fu & 1) == 0)
            ast8(h1tag + (s & 63) * 4096 + fb * 256 + blk * 8 + (fu >> 1), pack2b(h, hn, (unsigned)s));
        }
      }
    } else {
      float* prt = (float*)(A32 + 8192);    // 16KB at [32KB..48KB)
      short8 bw[4][8];
      #pragma unroll
      for(int n = 0; n < 4; ++n){
        const long wrow = (long)(n * 512 + ubase + lu);
        #pragma unroll
        for(int i = 0; i < 8; ++i){
          int kk = w * 256 + i * 32 + kq * 8;
          const float* p = (kk < 512) ? (w_ih2 + wrow * 512 + kk)
                                      : (w_hh2 + wrow * 512 + (kk - 512));
          bw[n][i] = ld_bf16frag(p);
        }
      }
      for(int s = 1; s <= 255; ++s){
        const ull* s1 = h1tag + (s & 63) * 4096;
        const ull* s2 = h2tag + ((s - 1) & 63) * 4096;
        const unsigned w1 = (unsigned)s, w2 = (unsigned)(s - 1);
        ull v1[16], v2[16];
        #pragma unroll
        for(int j = 0; j < 16; ++j) v1[j] = ald8(s1 + tid + 256 * j);
        #pragma unroll
        for(int j = 0; j < 16; ++j) v2[j] = ald8(s2 + tid + 256 * j);
        for(;;){
          bool bad = false;
          #pragma unroll
          for(int j = 0; j < 16; ++j)
            if((unsigned)(v1[j] >> 32) != w1){ v1[j] = ald8(s1 + tid + 256 * j); bad = true; }
          if(!bad) break;
        }
        for(;;){
          bool bad = false;
          #pragma unroll
          for(int j = 0; j < 16; ++j)
            if((unsigned)(v2[j] >> 32) != w2){ v2[j] = ald8(s2 + tid + 256 * j); bad = true; }
          if(!bad) break;
        }
        #pragma unroll
        for(int j = 0; j < 16; ++j){
          int wd = tid + 256 * j, b = wd >> 8, pr = wd & 255;
          int sw = (((pr >> 2) ^ (b & 7)) << 2) + (pr & 3);
          A32[b * 512 + sw] = (unsigned)v1[j];
          A32[b * 512 + 256 + sw] = (unsigned)v2[j];
        }
        __syncthreads();                    // B1
        f32x4 acc[4] = {};
        #pragma unroll
        for(int i = 0; i < 8; ++i){
          int k8 = w * 32 + i * 4 + kq;
          const short8* ap = (const short8*)(A16 + lu * 1024 + ((k8 ^ (lu & 7)) << 3));
          #pragma unroll
          for(int n = 0; n < 4; ++n)
            acc[n] = __builtin_amdgcn_mfma_f32_16x16x32_bf16(*ap, bw[n][i], acc[n], 0, 0, 0);
        }
        #pragma unroll
        for(int n = 0; n < 4; ++n)
          #pragma unroll
          for(int j = 0; j < 4; ++j)
            prt[w * 1024 + n * 256 + (kq * 4 + j) * 16 + lu] = acc[n][j];
        __syncthreads();                    // B2
        {
          float g4[4];
          #pragma unroll
          for(int g = 0; g < 4; ++g){
            int c = g * 256 + fb * 16 + fu;
            g4[g] = ag[g] + prt[c] + prt[1024 + c] + prt[2048 + c] + prt[3072 + c];
          }
          cst = sigm(g4[1]) * cst + sigm(g4[0]) * tanhf(g4[2]);
          float h = sigm(g4[3]) * tanhf(cst);
          float hn = __shfl(h, tid + 1);
          if((fu & 1) == 0){
            ast8(h2tag + (s & 63) * 4096 + fb * 256 + blk * 8 + (fu >> 1), pack2b(h, hn, (unsigned)s));
            // coherent packed h2bf write (read by proj workers via L3)
            asti((int*)(h2bf + ((long)s * 16 + fb) * 512 + ubase + fu),
                 (int)((unsigned)f2bf(h) | ((unsigned)f2bf(hn) << 16)));
          }
        }
        __syncthreads();                    // release: h2bf/h2tag stores drained
        if(tid == 0) asti(prog2 + blk * 16, s);
      }
    }
  }

  // ---- all blocks: drain projection tiles (progress-gated) ----
  proj_worker(A32, h2bf, embed_bf, fc_b, out, prog2, ctr, tid);
}

extern "C" void kernel_launch(void* const* d_in, const int* in_sizes, int n_in,
                              void* d_out, int out_size, void* d_ws, size_t ws_size,
                              hipStream_t stream){
  const int*   words = (const int*)  d_in[0];
  const float* embed = (const float*)d_in[1];
  const float* fc_b  = (const float*)d_in[2];
  const float* w_ih1 = (const float*)d_in[3];
  const float* w_hh1 = (const float*)d_in[4];
  const float* b_ih1 = (const float*)d_in[5];
  const float* b_hh1 = (const float*)d_in[6];
  const float* w_ih2 = (const float*)d_in[7];
  const float* w_hh2 = (const float*)d_in[8];
  const float* b_ih2 = (const float*)d_in[9];
  const float* b_hh2 = (const float*)d_in[10];
  float* out = (float*)d_out;
  char* ws = (char*)d_ws;

  unsigned short* embed_bf = (unsigned short*)(ws + 0);          // 32,768,000 B
  unsigned short* h2bf     = (unsigned short*)(ws + 32768000);   //  4,194,304 B (4096x512)
  ull* h1tag = (ull*)(ws + 36962304);                            //  2,097,152 B (64 x 4096 ull)
  ull* h2tag = (ull*)(ws + 39059456);                            //  2,097,152 B
  float* a1c = (float*)(ws + 41156608);                          //    131,072 B (16x2048)
  float* b2c = (float*)(ws + 41287680);                          //      8,192 B
  int*   done = (int*) (ws + 41295872);                          //     16,384 B (4096 ints)
  // total 41,312,256 B

  k_embed_cvt<<<16000, 256, 0, stream>>>(embed, embed_bf);
  k_prep_misc<<<32, 256, 0, stream>>>(b_ih2, b_hh2, b2c, h1tag, h2tag, h2bf, done);
  k_a1const<<<128, 256, 0, stream>>>(words, embed, w_ih1, b_ih1, b_hh1, a1c);

  // Fused recurrence + projection. No grid.sync -> coop launch with plain fallback
  // (the R3..R9 silent-failure fix).
  void* args[12];
  args[0] = (void*)&w_hh1; args[1] = (void*)&w_ih2; args[2] = (void*)&w_hh2;
  args[3] = (void*)&a1c;   args[4] = (void*)&b2c;
  args[5] = (void*)&h1tag; args[6] = (void*)&h2tag; args[7] = (void*)&h2bf;
  args[8] = (void*)&done;  args[9] = (void*)&embed_bf;
  args[10] = (void*)&fc_b; args[11] = (void*)&out;
  hipError_t ce = hipLaunchCooperativeKernel((const void*)k_recur, dim3(256), dim3(256),
                                             args, 0, stream);
  if(ce != hipSuccess){
    k_recur<<<dim3(256), dim3(256), 0, stream>>>(w_hh1, w_ih2, w_hh2, a1c, b2c,
                                                 h1tag, h2tag, h2bf, done,
                                                 embed_bf, fc_b, out);
  }
}